// Round 10
// baseline (218.481 us; speedup 1.0000x reference)
//
#include <hip/hip_runtime.h>

constexpr int N_NODES = 100000;
constexpr int N_EDGES = 1000000;
constexpr int DIM = 64;

constexpr int BNODES = 256;                                  // nodes per bucket
constexpr int NBUCK  = (N_NODES + BNODES - 1) / BNODES;      // 391
constexpr int SCAP   = 3072;                                 // pairs/bucket cap (lam=2558, +10 sigma)
constexpr int CHUNK  = 2048;                                 // edges per bin WG
constexpr int EPT    = 8;                                    // edges per thread
constexpr int NWG_A  = (N_EDGES + CHUNK - 1) / CHUNK;        // 489

constexpr int CAP  = 16;      // per-node neighbor slots; deg>16 -> exact fixup
constexpr int MAXO = 16384;   // overflow pair list (expected ~8k)
constexpr int SENT = 0x1FFFF; // sentinel j: >= N_NODES, routes load to zrow

constexpr int TILE = 64;      // nodes per fused block
constexpr int PAD  = 65;      // LDS row stride (floats)

// --- Phase A: bucket-partition edges, ONE edge read, rank-from-histogram ----
// (unchanged from r9 — control kernel; target next round once visible)
__global__ __launch_bounds__(256) void bin_edges(
    const int* __restrict__ eidx, int* __restrict__ gcur,
    int* __restrict__ staging)
{
    __shared__ int hist[NBUCK];
    __shared__ int gbase[NBUCK];

    const int tid = threadIdx.x;
    const int e0  = blockIdx.x * CHUNK;

    for (int t = tid; t < NBUCK; t += 256) hist[t] = 0;

    int iv[EPT], jv[EPT], rk[EPT];
#pragma unroll
    for (int u = 0; u < EPT; ++u) {
        int e = e0 + u * 256 + tid;
        bool ok = (e < N_EDGES);
        iv[u] = ok ? eidx[e] : -1;
        jv[u] = ok ? eidx[N_EDGES + e] : 0;
    }
    __syncthreads();

#pragma unroll
    for (int u = 0; u < EPT; ++u)
        if (iv[u] >= 0) rk[u] = atomicAdd(&hist[iv[u] >> 8], 1);
    __syncthreads();

    for (int t = tid; t < NBUCK; t += 256) {
        int c = hist[t];
        gbase[t] = (c > 0) ? atomicAdd(&gcur[t], c) : 0;
    }
    __syncthreads();

#pragma unroll
    for (int u = 0; u < EPT; ++u) {
        if (iv[u] >= 0) {
            int bk  = iv[u] >> 8;
            int dst = gbase[bk] + rk[u];
            if (dst < SCAP)
                staging[bk * SCAP + dst] = ((iv[u] & 255) << 17) | jv[u];
        }
    }
}

// --- Phase A2: slotify (HALF-bucket grain: 782 blocks = 2x TLP vs r9) -------
// Slot rows are pre-filled with SENT so the gather needs no predication:
// pad entries route the load to a zeroed row (zrow) via a SCALAR base select.
__global__ __launch_bounds__(256) void slotify(
    const int* __restrict__ gcur, const int* __restrict__ staging,
    int* __restrict__ noflow, int* __restrict__ oflow,
    int* __restrict__ deg_g, int* __restrict__ slot_g)
{
    constexpr int HN = 128;                  // nodes per half-bucket
    __shared__ int lcnt[HN];
    __shared__ int lsl[HN * CAP];            // 8 KB

    const int tid  = threadIdx.x;
    const int bk   = blockIdx.x >> 1;
    const int half = blockIdx.x & 1;

    if (tid < HN) lcnt[tid] = 0;
    {   // SENT-fill: 2048 ints / 256 threads = 2 int4 each
        int4 s4 = make_int4(SENT, SENT, SENT, SENT);
        reinterpret_cast<int4*>(lsl)[tid] = s4;
        reinterpret_cast<int4*>(lsl)[tid + 256] = s4;
    }
    __syncthreads();

    int m = gcur[bk];
    if (m > SCAP) m = SCAP;
    const int sg = bk * SCAP;
    for (int t = tid; t < m; t += 256) {
        int pk  = staging[sg + t];
        int off = pk >> 17;                  // 0..255 within bucket
        if ((off >> 7) == half) {
            int r = off & 127;
            int pos = atomicAdd(&lcnt[r], 1);
            if (pos < CAP) {
                lsl[(r << 4) + pos] = pk & 0x1FFFF;
            } else {
                int o = atomicAdd(noflow, 1);
                if (o < MAXO) {
                    oflow[2 * o]     = (bk << 8) + off;   // global node id
                    oflow[2 * o + 1] = pk & 0x1FFFF;      // source j
                }
            }
        }
    }
    __syncthreads();

    const int nb = (bk << 8) + (half << 7);  // first node of this half
    // write 128 rows x 16 ints = 512 int4, 2 per thread
#pragma unroll
    for (int w = 0; w < 2; ++w) {
        int q = tid + w * 256;               // int4 index 0..511
        int node = nb + (q >> 2);
        if (node < N_NODES)
            reinterpret_cast<int4*>(slot_g + ((size_t)nb << 4))[q] =
                reinterpret_cast<const int4*>(lsl)[q];
    }
    if (tid < HN) {
        int node = nb + tid;
        if (node < N_NODES) deg_g[node] = lcnt[tid];
    }
}

// --- Phase B (fused): gather mean + 64x64 matmul + bias ---------------------
// Gather upgrades vs r9 (58us, VALUBusy 44%):
//  (1) wave-uniform j -> readfirstlane -> SGPR base: loads are saddr-form
//      global_load_dword v, lane*4, s[base] — deletes per-lane 64-bit addr math.
//  (2) SENT slots select the zrow base with a SCALAR cselect — the 16
//      v_cndmask+adds per node become unconditional adds.
//  (3) 2-node interleave: 32 scalar loads in flight per wave (vs 16).
__global__ __launch_bounds__(256) void fused_gather_mm(
    const float* __restrict__ x, const float* __restrict__ zrow,
    const int* __restrict__ deg_g, const int* __restrict__ slot_g,
    const float* __restrict__ W, const float* __restrict__ b,
    float* __restrict__ out)
{
    __shared__ float tile[TILE * PAD];       // 16.6 KB
    __shared__ int   lslot[TILE * CAP];      // 4 KB
    __shared__ int   ldeg[TILE];

    const int tid  = threadIdx.x;
    const int base = blockIdx.x * TILE;
    const int lane = tid & 63;
    const int wid  = tid >> 6;               // 0..3

    // stage 64 slot rows (4 KB, coalesced int4) + degrees; OOB rows -> SENT
    {
        const int stg_row = base + (tid >> 2);
        int4 v;
        if (stg_row < N_NODES)
            v = reinterpret_cast<const int4*>(slot_g + ((size_t)base << 4))[tid];
        else
            v = make_int4(SENT, SENT, SENT, SENT);
        reinterpret_cast<int4*>(lslot)[tid] = v;
        if (tid < TILE) {
            int g = base + tid;
            ldeg[tid] = (g < N_NODES) ? deg_g[g] : 0;
        }
    }
    __syncthreads();

    // ---- gather: 2 nodes interleaved, 32 scalar loads in flight ----
    for (int p = 0; p < 8; ++p) {
        const int rowA = wid * 16 + 2 * p;
        const int rowB = rowA + 1;

        float va[16], vb[16];
#pragma unroll
        for (int u = 0; u < 16; ++u) {
            const int jA = __builtin_amdgcn_readfirstlane(lslot[(rowA << 4) + u]);
            const int jB = __builtin_amdgcn_readfirstlane(lslot[(rowB << 4) + u]);
            const float* pA = (jA == SENT) ? zrow : x + ((size_t)jA << 6);
            const float* pB = (jB == SENT) ? zrow : x + ((size_t)jB << 6);
            va[u] = pA[lane];                // saddr + lane*4: zero VALU addr math
            vb[u] = pB[lane];
        }

        float sA = 0.0f, sB = 0.0f;
#pragma unroll
        for (int u = 0; u < 16; ++u) { sA += va[u]; sB += vb[u]; }

        const int dA = ldeg[rowA], dB = ldeg[rowB];
        const float invA = (dA > 0) ? 1.0f / (float)dA : 0.0f;
        const float invB = (dB > 0) ? 1.0f / (float)dB : 0.0f;
        tile[rowA * PAD + lane] = sA * invA;
        tile[rowB * PAD + lane] = sB * invB;
    }
    __syncthreads();

    // ---- matmul: acc[q] = sum_k agg[nd][k] * W[d0+q][k] ----
    const int nd  = tid & 63;
    const int d0u = __builtin_amdgcn_readfirstlane((tid >> 6) << 4);
    const float* __restrict__ Wr = W + (size_t)d0u * DIM;   // uniform -> s_load

    float acc[16];
#pragma unroll
    for (int q = 0; q < 16; ++q) acc[q] = 0.0f;

#pragma unroll 4
    for (int k = 0; k < DIM; ++k) {
        float a = tile[nd * PAD + k];        // lane*65+k: conflict-free
#pragma unroll
        for (int q = 0; q < 16; ++q)
            acc[q] = fmaf(a, Wr[(size_t)q * DIM + k], acc[q]);
    }

    // ---- epilogue: mask + bias, LDS round-trip for coalesced store ----
    const int dg = ldeg[nd];
    __syncthreads();                         // everyone done reading agg
#pragma unroll
    for (int q = 0; q < 16; ++q) {
        float v2 = (dg > 0) ? (acc[q] + b[d0u + q]) : 0.0f;
        tile[nd * PAD + d0u + q] = v2;
    }
    __syncthreads();

#pragma unroll
    for (int r = 0; r < 16; ++r) {
        int idx = r * 256 + tid;             // 0..4095
        int row = idx >> 6, d = idx & 63;
        int g = base + row;
        if (g < N_NODES)
            out[(size_t)g * DIM + d] = tile[row * PAD + d];
    }
}

// --- Phase C: exact fixup for deg>16 overflow (~8k edges expected) ----------
__global__ __launch_bounds__(256) void fixup_overflow(
    const int* __restrict__ noflow, const int* __restrict__ oflow,
    const int* __restrict__ deg_g, const float* __restrict__ x,
    const float* __restrict__ W, float* __restrict__ out)
{
    int m = *noflow;
    if (m > MAXO) m = MAXO;
    const int lane = threadIdx.x & 63;
    const int wv   = (blockIdx.x * 256 + threadIdx.x) >> 6;
    const int nwv  = (gridDim.x * 256) >> 6;
    const float* __restrict__ wr = W + ((size_t)lane << 6);
    for (int o = wv; o < m; o += nwv) {
        const int i = oflow[2 * o];
        const int j = oflow[2 * o + 1];
        const float inv = 1.0f / (float)deg_g[i];
        const float* __restrict__ xr = x + ((size_t)j << 6);
        float acc = 0.0f;
#pragma unroll
        for (int k4 = 0; k4 < 16; ++k4) {
            const float4 xv  = *reinterpret_cast<const float4*>(xr + 4 * k4);
            const float4 wv4 = *reinterpret_cast<const float4*>(wr + 4 * k4);
            acc = fmaf(xv.x, wv4.x, acc);
            acc = fmaf(xv.y, wv4.y, acc);
            acc = fmaf(xv.z, wv4.z, acc);
            acc = fmaf(xv.w, wv4.w, acc);
        }
        atomicAdd(&out[((size_t)i << 6) + lane], acc * inv);
    }
}

extern "C" void kernel_launch(void* const* d_in, const int* in_sizes, int n_in,
                              void* d_out, int out_size, void* d_ws, size_t ws_size,
                              hipStream_t stream) {
    const float* x  = (const float*)d_in[0];   // (N, 64)
    const int*   ei = (const int*)d_in[1];     // (2, E): [0,E) targets, [E,2E) sources
    const float* W  = (const float*)d_in[2];   // (64, 64)
    const float* b  = (const float*)d_in[3];   // (64,)
    float* out = (float*)d_out;                // (N, 64)

    // Workspace layout (~11.7 MB, same as r9 which passed)
    int* gcur    = (int*)d_ws;                 // NBUCK
    int* noflow  = gcur + NBUCK;               // 1
    float* zrow  = (float*)(noflow + 1);       // 64 zero floats (memset'd)
    int* oflow   = (int*)(zrow + 64);          // 2*MAXO
    int* deg_g   = oflow + 2 * MAXO;           // N_NODES
    int* slot_g  = deg_g + N_NODES;            // N_NODES*16 + 1024 pad
    int* staging = slot_g + N_NODES * 16 + 1024;   // NBUCK * SCAP

    // one memset covers gcur + noflow + zrow
    hipMemsetAsync(gcur, 0, (NBUCK + 1 + 64) * sizeof(int), stream);

    bin_edges<<<NWG_A, 256, 0, stream>>>(ei, gcur, staging);
    slotify<<<NBUCK * 2, 256, 0, stream>>>(gcur, staging, noflow, oflow, deg_g, slot_g);
    fused_gather_mm<<<(N_NODES + TILE - 1) / TILE, 256, 0, stream>>>(
        x, zrow, deg_g, slot_g, W, b, out);
    fixup_overflow<<<128, 256, 0, stream>>>(noflow, oflow, deg_g, x, W, out);
}